// Round 4
// baseline (128.264 us; speedup 1.0000x reference)
//
#include <hip/hip_runtime.h>

#define H 1024
#define W 1024
#define NC 12   // channels
#define ND 8    // depth
#define HG 16
#define WG 16

typedef float v2f __attribute__((ext_vector_type(2)));

// One block per (n, y, half-row). wy is block-uniform: y-interp folded into
// LDS staging (sg[x][z][c], 6 KB). Main loop: bilinear (x,z), 12 ds_read_b128
// per pixel, 2 pixels/thread, stores interleaved per channel-group to keep
// VGPR pressure low (target 6 waves/SIMD occupancy).
__global__ __launch_bounds__(256, 6) void slice_kernel(
    const float* __restrict__ grid,
    const float* __restrict__ guide,
    float* __restrict__ out)
{
    const int xh  = blockIdx.x;   // half-row: 0 or 1
    const int y   = blockIdx.y;
    const int n   = blockIdx.z;
    const int tid = threadIdx.x;

    // Per-row y interpolation (block-uniform), mirroring the reference math.
    float yn = -1.0f + 2.0f * (float)y / (float)(H - 1);
    float iy = (yn + 1.0f) * 0.5f * (float)(HG - 1);
    iy = fminf(fmaxf(iy, 0.0f), (float)(HG - 1));
    int   iy0 = (int)floorf(iy);
    int   iy1 = min(iy0 + 1, HG - 1);
    float wy  = iy - (float)iy0;

    // LDS: y-interpolated grid row, layout [x(16)][z(8)][c(12)] = 1536 f = 6 KB
    __shared__ __align__(16) float sg[WG * ND * NC];
    const float* gbase = grid + (size_t)n * NC * ND * HG * WG;
    for (int i = tid; i < WG * ND * NC; i += 256) {
        int x  = i & (WG - 1);
        int zc = i >> 4;
        int z  = zc & (ND - 1);
        int c  = zc >> 3;
        const float* gp = gbase + ((c * ND + z) * HG) * WG + x;
        float r0 = gp[iy0 * WG];
        float r1 = gp[iy1 * WG];
        sg[(x * ND + z) * NC + c] = r0 + (r1 - r0) * wy;
    }
    __syncthreads();

    const int xb = xh * (W / 2) + tid * 2;        // 2 consecutive pixels/thread
    const float* gd = guide + ((size_t)n * H + y) * W;
    float*       ob = out + ((size_t)n * NC * H + y) * W;  // + c*H*W + x

    const float2 g2 = *(const float2*)&gd[xb];
    const float gz[2] = {g2.x, g2.y};

    int   B0[2], B1[2], Z0[2], Z1[2];
    float wxv[2], wzv[2];

    #pragma unroll
    for (int p = 0; p < 2; ++p) {
        const int x = xb + p;
        // x interpolation
        float xn = -1.0f + 2.0f * (float)x / (float)(W - 1);
        float ix = (xn + 1.0f) * 0.5f * (float)(WG - 1);
        ix = fminf(fmaxf(ix, 0.0f), (float)(WG - 1));
        int   ix0 = (int)floorf(ix);
        int   ix1 = min(ix0 + 1, WG - 1);
        wxv[p] = ix - (float)ix0;

        // z from guide
        float zn = gz[p] * 2.0f - 1.0f;
        float iz = (zn + 1.0f) * 0.5f * (float)(ND - 1);
        iz = fminf(fmaxf(iz, 0.0f), (float)(ND - 1));
        int   iz0 = (int)floorf(iz);
        int   iz1 = min(iz0 + 1, ND - 1);
        wzv[p] = iz - (float)iz0;

        B0[p] = ix0 * (ND * NC);
        B1[p] = ix1 * (ND * NC);
        Z0[p] = iz0 * NC;
        Z1[p] = iz1 * NC;
    }

    #pragma unroll
    for (int cc = 0; cc < NC; cc += 4) {
        float r[2][4];
        #pragma unroll
        for (int p = 0; p < 2; ++p) {
            const float wz = wzv[p], wx = wxv[p];
            const float4 a0 = *(const float4*)&sg[B0[p] + Z0[p] + cc];
            const float4 a1 = *(const float4*)&sg[B0[p] + Z1[p] + cc];
            const float4 b0 = *(const float4*)&sg[B1[p] + Z0[p] + cc];
            const float4 b1 = *(const float4*)&sg[B1[p] + Z1[p] + cc];

            float za, zb;
            za = a0.x + (a1.x - a0.x) * wz;
            zb = b0.x + (b1.x - b0.x) * wz;
            r[p][0] = za + (zb - za) * wx;

            za = a0.y + (a1.y - a0.y) * wz;
            zb = b0.y + (b1.y - b0.y) * wz;
            r[p][1] = za + (zb - za) * wx;

            za = a0.z + (a1.z - a0.z) * wz;
            zb = b0.z + (b1.z - b0.z) * wz;
            r[p][2] = za + (zb - za) * wx;

            za = a0.w + (a1.w - a0.w) * wz;
            zb = b0.w + (b1.w - b0.w) * wz;
            r[p][3] = za + (zb - za) * wx;
        }
        #pragma unroll
        for (int c = 0; c < 4; ++c) {
            v2f v = {r[0][c], r[1][c]};
            __builtin_nontemporal_store(v, (v2f*)&ob[(size_t)(cc + c) * H * W + xb]);
        }
    }
}

extern "C" void kernel_launch(void* const* d_in, const int* in_sizes, int n_in,
                              void* d_out, int out_size, void* d_ws, size_t ws_size,
                              hipStream_t stream) {
    const float* grid  = (const float*)d_in[0];
    const float* guide = (const float*)d_in[1];
    float* out = (float*)d_out;

    dim3 grd(2, H, 2);   // (half-row, y, n)
    dim3 blk(256);
    slice_kernel<<<grd, blk, 0, stream>>>(grid, guide, out);
}

// Round 5
// 118.767 us; speedup vs baseline: 1.0800x; 1.0800x over previous
//
#include <hip/hip_runtime.h>

#define H 1024
#define W 1024
#define NC 12   // channels
#define ND 8    // depth
#define HG 16
#define WG 16

// One block per (n, y). wy is block-uniform: y-interp folded into LDS staging
// (sg[x][z][c], 6 KB). Main loop: bilinear (x,z). Restructured cc-outer /
// pixel-inner: 16 independent ds_read_b128 per channel-group, stores
// interleaved per group (no res[12][4] array -> lower VGPR, more waves/SIMD).
__global__ __launch_bounds__(256, 4) void slice_kernel(
    const float* __restrict__ grid,
    const float* __restrict__ guide,
    float* __restrict__ out)
{
    const int y   = blockIdx.x;
    const int n   = blockIdx.y;
    const int tid = threadIdx.x;

    // Per-row y interpolation (block-uniform), mirroring the reference math.
    float yn = -1.0f + 2.0f * (float)y / (float)(H - 1);
    float iy = (yn + 1.0f) * 0.5f * (float)(HG - 1);
    iy = fminf(fmaxf(iy, 0.0f), (float)(HG - 1));
    int   iy0 = (int)floorf(iy);
    int   iy1 = min(iy0 + 1, HG - 1);
    float wy  = iy - (float)iy0;

    // LDS: y-interpolated grid row, layout [x(16)][z(8)][c(12)] = 1536 f = 6 KB
    __shared__ __align__(16) float sg[WG * ND * NC];
    const float* gbase = grid + (size_t)n * NC * ND * HG * WG;
    for (int i = tid; i < WG * ND * NC; i += 256) {
        int x  = i & (WG - 1);
        int zc = i >> 4;
        int z  = zc & (ND - 1);
        int c  = zc >> 3;
        const float* gp = gbase + ((c * ND + z) * HG) * WG + x;
        float r0 = gp[iy0 * WG];
        float r1 = gp[iy1 * WG];
        sg[(x * ND + z) * NC + c] = r0 + (r1 - r0) * wy;
    }
    __syncthreads();

    const int xb = tid * 4;                       // 4 consecutive pixels/thread
    const float* gd = guide + ((size_t)n * H + y) * W;
    float*       ob = out + ((size_t)n * NC * H + y) * W;  // + c*H*W + x

    const float4 g4 = *(const float4*)&gd[xb];
    const float gz[4] = {g4.x, g4.y, g4.z, g4.w};

    // Per-pixel corner base addresses (float indices into sg) and weights.
    int   A00[4], A01[4], A10[4], A11[4];
    float wxv[4], wzv[4];

    #pragma unroll
    for (int p = 0; p < 4; ++p) {
        const int x = xb + p;
        float xn = -1.0f + 2.0f * (float)x / (float)(W - 1);
        float ix = (xn + 1.0f) * 0.5f * (float)(WG - 1);
        ix = fminf(fmaxf(ix, 0.0f), (float)(WG - 1));
        int   ix0 = (int)floorf(ix);
        int   ix1 = min(ix0 + 1, WG - 1);
        wxv[p] = ix - (float)ix0;

        float zn = gz[p] * 2.0f - 1.0f;
        float iz = (zn + 1.0f) * 0.5f * (float)(ND - 1);
        iz = fminf(fmaxf(iz, 0.0f), (float)(ND - 1));
        int   iz0 = (int)floorf(iz);
        int   iz1 = min(iz0 + 1, ND - 1);
        wzv[p] = iz - (float)iz0;

        const int B0 = ix0 * (ND * NC);
        const int B1 = ix1 * (ND * NC);
        const int Z0 = iz0 * NC;
        const int Z1 = iz1 * NC;
        A00[p] = B0 + Z0;  A01[p] = B0 + Z1;
        A10[p] = B1 + Z0;  A11[p] = B1 + Z1;
    }

    #pragma unroll
    for (int cc = 0; cc < NC; cc += 4) {
        // q[p] = channel-vec (cc..cc+3) result for pixel p
        float4 q[4];
        #pragma unroll
        for (int p = 0; p < 4; ++p) {
            const float wz = wzv[p], wx = wxv[p];
            const float4 a0 = *(const float4*)&sg[A00[p] + cc];
            const float4 a1 = *(const float4*)&sg[A01[p] + cc];
            const float4 b0 = *(const float4*)&sg[A10[p] + cc];
            const float4 b1 = *(const float4*)&sg[A11[p] + cc];

            float za, zb;
            za = a0.x + (a1.x - a0.x) * wz;
            zb = b0.x + (b1.x - b0.x) * wz;
            q[p].x = za + (zb - za) * wx;

            za = a0.y + (a1.y - a0.y) * wz;
            zb = b0.y + (b1.y - b0.y) * wz;
            q[p].y = za + (zb - za) * wx;

            za = a0.z + (a1.z - a0.z) * wz;
            zb = b0.z + (b1.z - b0.z) * wz;
            q[p].z = za + (zb - za) * wx;

            za = a0.w + (a1.w - a0.w) * wz;
            zb = b0.w + (b1.w - b0.w) * wz;
            q[p].w = za + (zb - za) * wx;
        }
        {
            float4 v;
            v = make_float4(q[0].x, q[1].x, q[2].x, q[3].x);
            *(float4*)&ob[(size_t)(cc + 0) * H * W + xb] = v;
            v = make_float4(q[0].y, q[1].y, q[2].y, q[3].y);
            *(float4*)&ob[(size_t)(cc + 1) * H * W + xb] = v;
            v = make_float4(q[0].z, q[1].z, q[2].z, q[3].z);
            *(float4*)&ob[(size_t)(cc + 2) * H * W + xb] = v;
            v = make_float4(q[0].w, q[1].w, q[2].w, q[3].w);
            *(float4*)&ob[(size_t)(cc + 3) * H * W + xb] = v;
        }
    }
}

extern "C" void kernel_launch(void* const* d_in, const int* in_sizes, int n_in,
                              void* d_out, int out_size, void* d_ws, size_t ws_size,
                              hipStream_t stream) {
    const float* grid  = (const float*)d_in[0];
    const float* guide = (const float*)d_in[1];
    float* out = (float*)d_out;

    dim3 grd(H, 2);   // (y, n)
    dim3 blk(256);
    slice_kernel<<<grd, blk, 0, stream>>>(grid, guide, out);
}